// Round 3
// baseline (254.204 us; speedup 1.0000x reference)
//
#include <hip/hip_runtime.h>
#include <hip/hip_bf16.h>

#define NB   1024
#define SINQ 256
#define SPRQ 128
#define HIDQ 512

// pos_enc: emb[:, :3] = sin(pos * inv_freq[c]); inv_freq[c] = 10000^(-2c/256)
#define PEF1 0.93057207f
#define PEF2 0.86596438f
#define ISQ3 0.57735026919f

// ws layout (floats)
#define OFF_ENCKV   0                          // 1024*256*8
#define OFF_DECKV   (OFF_ENCKV + NB*SINQ*8)    // 1024*128*8
#define OFF_CROSSKV (OFF_DECKV + NB*SPRQ*8)    // 1024*256*8
#define OFF_FFNE    (OFF_CROSSKV + NB*SINQ*8)  // 512*8
#define OFF_FFND    (OFF_FFNE + HIDQ*8)        // 512*8

// Block-wide mean / rstd over (nthr threads * 3 values each) = nelem.
__device__ __forceinline__ void block_stats(float s1, float s2, float* sRed,
                                            int tid, int nthr, float nelem,
                                            float& mean, float& rstd) {
#pragma unroll
  for (int off = 32; off > 0; off >>= 1) {
    s1 += __shfl_xor(s1, off, 64);
    s2 += __shfl_xor(s2, off, 64);
  }
  __syncthreads();
  if ((tid & 63) == 0) {
    sRed[((tid >> 6) << 1) + 0] = s1;
    sRed[((tid >> 6) << 1) + 1] = s2;
  }
  __syncthreads();
  float t1 = 0.f, t2 = 0.f;
  const int nw = nthr >> 6;
  for (int w = 0; w < nw; ++w) { t1 += sRed[2 * w]; t2 += sRed[2 * w + 1]; }
  mean = t1 / nelem;
  float var = t2 / nelem - mean * mean;
  rstd = rsqrtf(var + 1e-5f);
}

// K1: compute enc K/V rows, dec self-attn K/V rows; block 0 packs FFN weights.
__global__ __launch_bounds__(384) void prep_kv(
    const float* __restrict__ X, const float* __restrict__ T,
    const float* __restrict__ einw, const float* __restrict__ einb,
    const float* __restrict__ a1w,  const float* __restrict__ a1b,
    const float* __restrict__ ew1, const float* __restrict__ eb1,
    const float* __restrict__ ew2,
    const float* __restrict__ dw1, const float* __restrict__ db1,
    const float* __restrict__ dw2,
    float* __restrict__ ws)
{
  const int b = blockIdx.x;
  const int t = threadIdx.x;

  if (b == 0) {  // pack FFN weight records: {w1_0,w1_1,w1_2,b1, w2r0,w2r1,w2r2, 0}
    for (int k = t; k < HIDQ; k += 384) {
      float4* fe = (float4*)(ws + OFF_FFNE) + 2 * k;
      fe[0] = make_float4(ew1[3 * k], ew1[3 * k + 1], ew1[3 * k + 2], eb1[k]);
      fe[1] = make_float4(ew2[k], ew2[HIDQ + k], ew2[2 * HIDQ + k], 0.f);
      float4* fd = (float4*)(ws + OFF_FFND) + 2 * k;
      fd[0] = make_float4(dw1[3 * k], dw1[3 * k + 1], dw1[3 * k + 2], db1[k]);
      fd[1] = make_float4(dw2[k], dw2[HIDQ + k], dw2[2 * HIDQ + k], 0.f);
    }
  }

  if (t < SINQ) {  // encoder K/V row t
    const int i = t;
    const float pos = (float)i;
    const float* xr = X + ((size_t)b * SINQ + i) * 3;
    const float p0 = xr[0] + sinf(pos);
    const float p1 = xr[1] + sinf(pos * PEF1);
    const float p2 = xr[2] + sinf(pos * PEF2);
    const float k0 = einw[9]  * p0 + einw[10] * p1 + einw[11] * p2 + einb[3];
    const float k1 = einw[12] * p0 + einw[13] * p1 + einw[14] * p2 + einb[4];
    const float k2 = einw[15] * p0 + einw[16] * p1 + einw[17] * p2 + einb[5];
    const float v0 = einw[18] * p0 + einw[19] * p1 + einw[20] * p2 + einb[6];
    const float v1 = einw[21] * p0 + einw[22] * p1 + einw[23] * p2 + einb[7];
    const float v2 = einw[24] * p0 + einw[25] * p1 + einw[26] * p2 + einb[8];
    float4* kv = (float4*)(ws + OFF_ENCKV) + 2 * ((size_t)b * SINQ + i);
    kv[0] = make_float4(k0, k1, k2, 0.f);
    kv[1] = make_float4(v0, v1, v2, 0.f);
  } else {  // decoder self-attn K/V row t-256
    const int i = t - SINQ;
    const float pos = (float)i;
    const float* tr = T + ((size_t)b * SPRQ + i) * 3;
    const float p0 = tr[0] + sinf(pos);
    const float p1 = tr[1] + sinf(pos * PEF1);
    const float p2 = tr[2] + sinf(pos * PEF2);
    const float k0 = a1w[9]  * p0 + a1w[10] * p1 + a1w[11] * p2 + a1b[3];
    const float k1 = a1w[12] * p0 + a1w[13] * p1 + a1w[14] * p2 + a1b[4];
    const float k2 = a1w[15] * p0 + a1w[16] * p1 + a1w[17] * p2 + a1b[5];
    const float v0 = a1w[18] * p0 + a1w[19] * p1 + a1w[20] * p2 + a1b[6];
    const float v1 = a1w[21] * p0 + a1w[22] * p1 + a1w[23] * p2 + a1b[7];
    const float v2 = a1w[24] * p0 + a1w[25] * p1 + a1w[26] * p2 + a1b[8];
    float4* kv = (float4*)(ws + OFF_DECKV) + 2 * ((size_t)b * SPRQ + i);
    kv[0] = make_float4(k0, k1, k2, 0.f);
    kv[1] = make_float4(v0, v1, v2, 0.f);
  }
}

// K2: encoder layer; emits decoder cross-attn K/V instead of enc_out.
__global__ __launch_bounds__(256) void enc_fwd(
    const float* __restrict__ X,
    const float* __restrict__ inw, const float* __restrict__ inb,
    const float* __restrict__ ow,  const float* __restrict__ ob,
    const float* __restrict__ ln1w, const float* __restrict__ ln1b,
    const float* __restrict__ b2,
    const float* __restrict__ ln2w, const float* __restrict__ ln2b,
    const float* __restrict__ a2w, const float* __restrict__ a2b,
    const float4* __restrict__ encKV,   // wave-uniform reads -> scalar path
    const float4* __restrict__ ffnE,    // wave-uniform reads -> scalar path
    float4* __restrict__ crossKV)
{
  __shared__ float sRed[8];
  const int b = blockIdx.x;
  const int i = threadIdx.x;

  const float pos = (float)i;
  const float* xr = X + ((size_t)b * SINQ + i) * 3;
  const float p0 = xr[0] + sinf(pos);
  const float p1 = xr[1] + sinf(pos * PEF1);
  const float p2 = xr[2] + sinf(pos * PEF2);

  // q, pre-scaled by 1/sqrt(3)
  const float q0 = (inw[0] * p0 + inw[1] * p1 + inw[2] * p2 + inb[0]) * ISQ3;
  const float q1 = (inw[3] * p0 + inw[4] * p1 + inw[5] * p2 + inb[1]) * ISQ3;
  const float q2 = (inw[6] * p0 + inw[7] * p1 + inw[8] * p2 + inb[2]) * ISQ3;

  // fused softmax(QK^T)@V; kv[j] is wave-uniform
  float den = 0.f, o0 = 0.f, o1 = 0.f, o2 = 0.f;
  const float4* kv = encKV + 2 * ((size_t)b * SINQ);
  for (int j = 0; j < SINQ; ++j) {
    const float4 kk = kv[2 * j];
    const float4 vv = kv[2 * j + 1];
    const float e = __expf(q0 * kk.x + q1 * kk.y + q2 * kk.z);
    den += e;
    o0 = fmaf(e, vv.x, o0); o1 = fmaf(e, vv.y, o1); o2 = fmaf(e, vv.z, o2);
  }
  const float rd = 1.f / den;
  o0 *= rd; o1 *= rd; o2 *= rd;

  float r0 = ow[0] * o0 + ow[1] * o1 + ow[2] * o2 + ob[0] + p0;
  float r1 = ow[3] * o0 + ow[4] * o1 + ow[5] * o2 + ob[1] + p1;
  float r2 = ow[6] * o0 + ow[7] * o1 + ow[8] * o2 + ob[2] + p2;

  float mean, rstd;
  block_stats(r0 + r1 + r2, r0 * r0 + r1 * r1 + r2 * r2, sRed, i, 256, 768.f, mean, rstd);
  const int li = i * 3;
  const float x20 = (r0 - mean) * rstd * ln1w[li + 0] + ln1b[li + 0];
  const float x21 = (r1 - mean) * rstd * ln1w[li + 1] + ln1b[li + 1];
  const float x22 = (r2 - mean) * rstd * ln1w[li + 2] + ln1b[li + 2];

  // FFN 3->512->3; weight records are wave-uniform
  float c0 = 0.f, c1 = 0.f, c2 = 0.f;
  for (int k = 0; k < HIDQ; ++k) {
    const float4 wr = ffnE[2 * k];
    const float4 wc = ffnE[2 * k + 1];
    float h = fmaf(wr.x, x20, fmaf(wr.y, x21, fmaf(wr.z, x22, wr.w)));
    h = fmaxf(h, 0.f);
    c0 = fmaf(h, wc.x, c0); c1 = fmaf(h, wc.y, c1); c2 = fmaf(h, wc.z, c2);
  }
  const float h0 = c0 + b2[0] + x20;
  const float h1 = c1 + b2[1] + x21;
  const float h2 = c2 + b2[2] + x22;

  block_stats(h0 + h1 + h2, h0 * h0 + h1 * h1 + h2 * h2, sRed, i, 256, 768.f, mean, rstd);
  const float e0 = (h0 - mean) * rstd * ln2w[li + 0] + ln2b[li + 0];
  const float e1 = (h1 - mean) * rstd * ln2w[li + 1] + ln2b[li + 1];
  const float e2 = (h2 - mean) * rstd * ln2w[li + 2] + ln2b[li + 2];

  // decoder cross-attn K/V for this enc_out row (a2w rows 3-5 = Wk, 6-8 = Wv)
  float4* ckv = crossKV + 2 * ((size_t)b * SINQ + i);
  ckv[0] = make_float4(a2w[9]  * e0 + a2w[10] * e1 + a2w[11] * e2 + a2b[3],
                       a2w[12] * e0 + a2w[13] * e1 + a2w[14] * e2 + a2b[4],
                       a2w[15] * e0 + a2w[16] * e1 + a2w[17] * e2 + a2b[5], 0.f);
  ckv[1] = make_float4(a2w[18] * e0 + a2w[19] * e1 + a2w[20] * e2 + a2b[6],
                       a2w[21] * e0 + a2w[22] * e1 + a2w[23] * e2 + a2b[7],
                       a2w[24] * e0 + a2w[25] * e1 + a2w[26] * e2 + a2b[8], 0.f);
}

// K3: decoder
__global__ __launch_bounds__(128) void dec_fwd(
    const float* __restrict__ T,
    const float* __restrict__ a1w, const float* __restrict__ a1b,
    const float* __restrict__ a1ow, const float* __restrict__ a1ob,
    const float* __restrict__ ln1w, const float* __restrict__ ln1b,
    const float* __restrict__ a2w, const float* __restrict__ a2b,
    const float* __restrict__ a2ow, const float* __restrict__ a2ob,
    const float* __restrict__ b2,
    const float* __restrict__ ln3w, const float* __restrict__ ln3b,
    const float4* __restrict__ decKV,
    const float4* __restrict__ crossKV,
    const float4* __restrict__ ffnD,
    float* __restrict__ out)
{
  __shared__ float sRed[8];
  const int b = blockIdx.x;
  const int i = threadIdx.x;

  const float pos = (float)i;
  const float* tr = T + ((size_t)b * SPRQ + i) * 3;
  const float p0 = tr[0] + sinf(pos);
  const float p1 = tr[1] + sinf(pos * PEF1);
  const float p2 = tr[2] + sinf(pos * PEF2);

  const float q0 = (a1w[0] * p0 + a1w[1] * p1 + a1w[2] * p2 + a1b[0]) * ISQ3;
  const float q1 = (a1w[3] * p0 + a1w[4] * p1 + a1w[5] * p2 + a1b[1]) * ISQ3;
  const float q2 = (a1w[6] * p0 + a1w[7] * p1 + a1w[8] * p2 + a1b[2]) * ISQ3;

  // self-attn: reference ADDS tril(ones) to scores
  float den = 0.f, o0 = 0.f, o1 = 0.f, o2 = 0.f;
  {
    const float4* kv = decKV + 2 * ((size_t)b * SPRQ);
    for (int j = 0; j < SPRQ; ++j) {
      const float4 kk = kv[2 * j];
      const float4 vv = kv[2 * j + 1];
      const float s = q0 * kk.x + q1 * kk.y + q2 * kk.z + ((j <= i) ? 1.f : 0.f);
      const float e = __expf(s);
      den += e;
      o0 = fmaf(e, vv.x, o0); o1 = fmaf(e, vv.y, o1); o2 = fmaf(e, vv.z, o2);
    }
  }
  float rd = 1.f / den;
  o0 *= rd; o1 *= rd; o2 *= rd;

  float r0 = a1ow[0] * o0 + a1ow[1] * o1 + a1ow[2] * o2 + a1ob[0] + p0;
  float r1 = a1ow[3] * o0 + a1ow[4] * o1 + a1ow[5] * o2 + a1ob[1] + p1;
  float r2 = a1ow[6] * o0 + a1ow[7] * o1 + a1ow[8] * o2 + a1ob[2] + p2;

  float mean, rstd;
  block_stats(r0 + r1 + r2, r0 * r0 + r1 * r1 + r2 * r2, sRed, i, 128, 384.f, mean, rstd);
  const int li = i * 3;
  const float x20 = (r0 - mean) * rstd * ln1w[li + 0] + ln1b[li + 0];
  const float x21 = (r1 - mean) * rstd * ln1w[li + 1] + ln1b[li + 1];
  const float x22 = (r2 - mean) * rstd * ln1w[li + 2] + ln1b[li + 2];

  // cross-attn
  const float cq0 = (a2w[0] * x20 + a2w[1] * x21 + a2w[2] * x22 + a2b[0]) * ISQ3;
  const float cq1 = (a2w[3] * x20 + a2w[4] * x21 + a2w[5] * x22 + a2b[1]) * ISQ3;
  const float cq2 = (a2w[6] * x20 + a2w[7] * x21 + a2w[8] * x22 + a2b[2]) * ISQ3;
  den = 0.f; o0 = 0.f; o1 = 0.f; o2 = 0.f;
  {
    const float4* kv = crossKV + 2 * ((size_t)b * SINQ);
    for (int j = 0; j < SINQ; ++j) {
      const float4 kk = kv[2 * j];
      const float4 vv = kv[2 * j + 1];
      const float e = __expf(cq0 * kk.x + cq1 * kk.y + cq2 * kk.z);
      den += e;
      o0 = fmaf(e, vv.x, o0); o1 = fmaf(e, vv.y, o1); o2 = fmaf(e, vv.z, o2);
    }
  }
  rd = 1.f / den;
  o0 *= rd; o1 *= rd; o2 *= rd;

  r0 = a2ow[0] * o0 + a2ow[1] * o1 + a2ow[2] * o2 + a2ob[0] + x20;
  r1 = a2ow[3] * o0 + a2ow[4] * o1 + a2ow[5] * o2 + a2ob[1] + x21;
  r2 = a2ow[6] * o0 + a2ow[7] * o1 + a2ow[8] * o2 + a2ob[2] + x22;

  // x3 = LN(a + x2) with dec_ln1 weights AGAIN (per reference)
  block_stats(r0 + r1 + r2, r0 * r0 + r1 * r1 + r2 * r2, sRed, i, 128, 384.f, mean, rstd);
  const float x30 = (r0 - mean) * rstd * ln1w[li + 0] + ln1b[li + 0];
  const float x31 = (r1 - mean) * rstd * ln1w[li + 1] + ln1b[li + 1];
  const float x32 = (r2 - mean) * rstd * ln1w[li + 2] + ln1b[li + 2];

  float c0 = 0.f, c1 = 0.f, c2 = 0.f;
  for (int k = 0; k < HIDQ; ++k) {
    const float4 wr = ffnD[2 * k];
    const float4 wc = ffnD[2 * k + 1];
    float h = fmaf(wr.x, x30, fmaf(wr.y, x31, fmaf(wr.z, x32, wr.w)));
    h = fmaxf(h, 0.f);
    c0 = fmaf(h, wc.x, c0); c1 = fmaf(h, wc.y, c1); c2 = fmaf(h, wc.z, c2);
  }
  const float h0 = c0 + b2[0] + x30;
  const float h1 = c1 + b2[1] + x31;
  const float h2 = c2 + b2[2] + x32;

  block_stats(h0 + h1 + h2, h0 * h0 + h1 * h1 + h2 * h2, sRed, i, 128, 384.f, mean, rstd);
  float* op = out + ((size_t)b * SPRQ + i) * 3;
  op[0] = (h0 - mean) * rstd * ln3w[li + 0] + ln3b[li + 0];
  op[1] = (h1 - mean) * rstd * ln3w[li + 1] + ln3b[li + 1];
  op[2] = (h2 - mean) * rstd * ln3w[li + 2] + ln3b[li + 2];
}

extern "C" void kernel_launch(void* const* d_in, const int* in_sizes, int n_in,
                              void* d_out, int out_size, void* d_ws, size_t ws_size,
                              hipStream_t stream) {
  (void)in_sizes; (void)n_in; (void)out_size; (void)ws_size;
  float* ws = (float*)d_ws;  // needs ~21 MB

  prep_kv<<<NB, 384, 0, stream>>>(
      (const float*)d_in[0], (const float*)d_in[1],
      (const float*)d_in[2], (const float*)d_in[3],
      (const float*)d_in[14], (const float*)d_in[15],
      (const float*)d_in[8], (const float*)d_in[9], (const float*)d_in[10],
      (const float*)d_in[24], (const float*)d_in[25], (const float*)d_in[26],
      ws);

  enc_fwd<<<NB, 256, 0, stream>>>(
      (const float*)d_in[0],
      (const float*)d_in[2],  (const float*)d_in[3],
      (const float*)d_in[4],  (const float*)d_in[5],
      (const float*)d_in[6],  (const float*)d_in[7],
      (const float*)d_in[11],
      (const float*)d_in[12], (const float*)d_in[13],
      (const float*)d_in[20], (const float*)d_in[21],
      (const float4*)(ws + OFF_ENCKV),
      (const float4*)(ws + OFF_FFNE),
      (float4*)(ws + OFF_CROSSKV));

  dec_fwd<<<NB, 128, 0, stream>>>(
      (const float*)d_in[1],
      (const float*)d_in[14], (const float*)d_in[15],
      (const float*)d_in[16], (const float*)d_in[17],
      (const float*)d_in[18], (const float*)d_in[19],
      (const float*)d_in[20], (const float*)d_in[21],
      (const float*)d_in[22], (const float*)d_in[23],
      (const float*)d_in[27],
      (const float*)d_in[28], (const float*)d_in[29],
      (const float4*)(ws + OFF_DECKV),
      (const float4*)(ws + OFF_CROSSKV),
      (const float4*)(ws + OFF_FFND),
      (float*)d_out);
}

// Round 4
// 231.225 us; speedup vs baseline: 1.0994x; 1.0994x over previous
//
#include <hip/hip_runtime.h>
#include <hip/hip_bf16.h>

#define NB   1024
#define SINQ 256
#define SPRQ 128
#define HIDQ 512

// pos_enc: emb[:, :3] = sin(pos * inv_freq[c]); inv_freq[c] = 10000^(-2c/256)
#define PEF1  0.93057207f
#define PEF2  0.86596438f
#define LOG2E 1.44269504089f
// q pre-scale: 1/sqrt(3) * log2(e)  (exp(x/sqrt3) == exp2(x*QS))
#define QS    0.83298066476f

// Wave-wide (block == 64 threads) mean/rstd over nelem values.
__device__ __forceinline__ void wave_stats(float s1, float s2, float nelem,
                                           float& mean, float& rstd) {
#pragma unroll
  for (int off = 32; off > 0; off >>= 1) {
    s1 += __shfl_xor(s1, off, 64);
    s2 += __shfl_xor(s2, off, 64);
  }
  mean = s1 / nelem;
  rstd = rsqrtf(s2 / nelem - mean * mean + 1e-5f);
}

// One block (64 threads = 1 wave) per batch element. Q=4 enc rows/thread,
// Q=2 dec rows/thread: the uniform KV/FFN stream is read once per wave and
// amortized over 4 (resp. 2) queries -> VALU-bound, not stream-bound.
__global__ __launch_bounds__(64) void fused_fwd(
    const float* __restrict__ X, const float* __restrict__ T,
    const float* __restrict__ einw, const float* __restrict__ einb,
    const float* __restrict__ eow,  const float* __restrict__ eob,
    const float* __restrict__ eln1w, const float* __restrict__ eln1b,
    const float* __restrict__ ew1, const float* __restrict__ eb1,
    const float* __restrict__ ew2, const float* __restrict__ eb2,
    const float* __restrict__ eln2w, const float* __restrict__ eln2b,
    const float* __restrict__ a1w, const float* __restrict__ a1b,
    const float* __restrict__ a1ow, const float* __restrict__ a1ob,
    const float* __restrict__ dln1w, const float* __restrict__ dln1b,
    const float* __restrict__ a2w, const float* __restrict__ a2b,
    const float* __restrict__ a2ow, const float* __restrict__ a2ob,
    const float* __restrict__ dw1, const float* __restrict__ db1,
    const float* __restrict__ dw2, const float* __restrict__ db2,
    const float* __restrict__ dln3w, const float* __restrict__ dln3b,
    float* __restrict__ out)
{
  __shared__ float4 sEncKV[2 * SINQ];   // 8 KB  {K,V} per row
  __shared__ float4 sFFN[2 * HIDQ];     // 16 KB {w1,b1},{w2,0}; enc then dec
  __shared__ float4 sDecKV[2 * SPRQ];   // 4 KB
  __shared__ float4 sCrossKV[2 * SINQ]; // 8 KB

  const int b = blockIdx.x;
  const int t = threadIdx.x;  // 0..63

  // ---- stage enc FFN weights (distributed, 8 recs/thread)
  for (int k = t; k < HIDQ; k += 64) {
    sFFN[2 * k]     = make_float4(ew1[3 * k], ew1[3 * k + 1], ew1[3 * k + 2], eb1[k]);
    sFFN[2 * k + 1] = make_float4(ew2[k], ew2[HIDQ + k], ew2[2 * HIDQ + k], 0.f);
  }

  // ---- enc rows i = t + 64r : p_X, q (pre-scaled), K/V -> LDS
  float p[4][3], q[4][3];
#pragma unroll
  for (int r = 0; r < 4; ++r) {
    const int i = t + 64 * r;
    const float pos = (float)i;
    const float* xr = X + ((size_t)b * SINQ + i) * 3;
    const float p0 = xr[0] + sinf(pos);
    const float p1 = xr[1] + sinf(pos * PEF1);
    const float p2 = xr[2] + sinf(pos * PEF2);
    p[r][0] = p0; p[r][1] = p1; p[r][2] = p2;
    q[r][0] = (einw[0] * p0 + einw[1] * p1 + einw[2] * p2 + einb[0]) * QS;
    q[r][1] = (einw[3] * p0 + einw[4] * p1 + einw[5] * p2 + einb[1]) * QS;
    q[r][2] = (einw[6] * p0 + einw[7] * p1 + einw[8] * p2 + einb[2]) * QS;
    sEncKV[2 * i] = make_float4(
        einw[9]  * p0 + einw[10] * p1 + einw[11] * p2 + einb[3],
        einw[12] * p0 + einw[13] * p1 + einw[14] * p2 + einb[4],
        einw[15] * p0 + einw[16] * p1 + einw[17] * p2 + einb[5], 0.f);
    sEncKV[2 * i + 1] = make_float4(
        einw[18] * p0 + einw[19] * p1 + einw[20] * p2 + einb[6],
        einw[21] * p0 + einw[22] * p1 + einw[23] * p2 + einb[7],
        einw[24] * p0 + einw[25] * p1 + einw[26] * p2 + einb[8], 0.f);
  }

  // ---- dec self-attn rows i = t + 64r : p_T, K/V -> LDS
  float pt[2][3];
#pragma unroll
  for (int r = 0; r < 2; ++r) {
    const int i = t + 64 * r;
    const float pos = (float)i;
    const float* tr = T + ((size_t)b * SPRQ + i) * 3;
    const float p0 = tr[0] + sinf(pos);
    const float p1 = tr[1] + sinf(pos * PEF1);
    const float p2 = tr[2] + sinf(pos * PEF2);
    pt[r][0] = p0; pt[r][1] = p1; pt[r][2] = p2;
    sDecKV[2 * i] = make_float4(
        a1w[9]  * p0 + a1w[10] * p1 + a1w[11] * p2 + a1b[3],
        a1w[12] * p0 + a1w[13] * p1 + a1w[14] * p2 + a1b[4],
        a1w[15] * p0 + a1w[16] * p1 + a1w[17] * p2 + a1b[5], 0.f);
    sDecKV[2 * i + 1] = make_float4(
        a1w[18] * p0 + a1w[19] * p1 + a1w[20] * p2 + a1b[6],
        a1w[21] * p0 + a1w[22] * p1 + a1w[23] * p2 + a1b[7],
        a1w[24] * p0 + a1w[25] * p1 + a1w[26] * p2 + a1b[8], 0.f);
  }
  __syncthreads();

  // ================= ENCODER =================
  // attention, Q=4 queries share each streamed KV row
  float den[4] = {0, 0, 0, 0}, o[4][3] = {};
  for (int j = 0; j < SINQ; ++j) {
    const float4 kk = sEncKV[2 * j];
    const float4 vv = sEncKV[2 * j + 1];
#pragma unroll
    for (int r = 0; r < 4; ++r) {
      const float e = exp2f(fmaf(q[r][0], kk.x, fmaf(q[r][1], kk.y, q[r][2] * kk.z)));
      den[r] += e;
      o[r][0] = fmaf(e, vv.x, o[r][0]);
      o[r][1] = fmaf(e, vv.y, o[r][1]);
      o[r][2] = fmaf(e, vv.z, o[r][2]);
    }
  }

  // out-proj + residual; LN over the full 768-elem slice (wave butterfly)
  float res[4][3];
  float s1 = 0.f, s2 = 0.f;
#pragma unroll
  for (int r = 0; r < 4; ++r) {
    const float rd = 1.f / den[r];
    const float o0 = o[r][0] * rd, o1 = o[r][1] * rd, o2 = o[r][2] * rd;
    res[r][0] = eow[0] * o0 + eow[1] * o1 + eow[2] * o2 + eob[0] + p[r][0];
    res[r][1] = eow[3] * o0 + eow[4] * o1 + eow[5] * o2 + eob[1] + p[r][1];
    res[r][2] = eow[6] * o0 + eow[7] * o1 + eow[8] * o2 + eob[2] + p[r][2];
#pragma unroll
    for (int c = 0; c < 3; ++c) { s1 += res[r][c]; s2 += res[r][c] * res[r][c]; }
  }
  float mean, rstd;
  wave_stats(s1, s2, 768.f, mean, rstd);
  float x2[4][3];
#pragma unroll
  for (int r = 0; r < 4; ++r) {
    const int li = (t + 64 * r) * 3;
#pragma unroll
    for (int c = 0; c < 3; ++c)
      x2[r][c] = (res[r][c] - mean) * rstd * eln1w[li + c] + eln1b[li + c];
  }

  // FFN 3->512->3, Q=4
  float fc[4][3] = {};
  for (int k = 0; k < HIDQ; ++k) {
    const float4 wr = sFFN[2 * k];
    const float4 wc = sFFN[2 * k + 1];
#pragma unroll
    for (int r = 0; r < 4; ++r) {
      float h = fmaf(wr.x, x2[r][0], fmaf(wr.y, x2[r][1], fmaf(wr.z, x2[r][2], wr.w)));
      h = fmaxf(h, 0.f);
      fc[r][0] = fmaf(h, wc.x, fc[r][0]);
      fc[r][1] = fmaf(h, wc.y, fc[r][1]);
      fc[r][2] = fmaf(h, wc.z, fc[r][2]);
    }
  }
  s1 = 0.f; s2 = 0.f;
#pragma unroll
  for (int r = 0; r < 4; ++r) {
#pragma unroll
    for (int c = 0; c < 3; ++c) {
      res[r][c] = fc[r][c] + eb2[c] + x2[r][c];
      s1 += res[r][c]; s2 += res[r][c] * res[r][c];
    }
  }
  wave_stats(s1, s2, 768.f, mean, rstd);

  // LN2 -> enc_out rows -> decoder cross-attn K/V straight into LDS
#pragma unroll
  for (int r = 0; r < 4; ++r) {
    const int i = t + 64 * r;
    const int li = i * 3;
    const float e0 = (res[r][0] - mean) * rstd * eln2w[li + 0] + eln2b[li + 0];
    const float e1 = (res[r][1] - mean) * rstd * eln2w[li + 1] + eln2b[li + 1];
    const float e2 = (res[r][2] - mean) * rstd * eln2w[li + 2] + eln2b[li + 2];
    sCrossKV[2 * i] = make_float4(
        a2w[9]  * e0 + a2w[10] * e1 + a2w[11] * e2 + a2b[3],
        a2w[12] * e0 + a2w[13] * e1 + a2w[14] * e2 + a2b[4],
        a2w[15] * e0 + a2w[16] * e1 + a2w[17] * e2 + a2b[5], 0.f);
    sCrossKV[2 * i + 1] = make_float4(
        a2w[18] * e0 + a2w[19] * e1 + a2w[20] * e2 + a2b[6],
        a2w[21] * e0 + a2w[22] * e1 + a2w[23] * e2 + a2b[7],
        a2w[24] * e0 + a2w[25] * e1 + a2w[26] * e2 + a2b[8], 0.f);
  }
  __syncthreads();

  // reuse the FFN slot for decoder FFN weights
  for (int k = t; k < HIDQ; k += 64) {
    sFFN[2 * k]     = make_float4(dw1[3 * k], dw1[3 * k + 1], dw1[3 * k + 2], db1[k]);
    sFFN[2 * k + 1] = make_float4(dw2[k], dw2[HIDQ + k], dw2[2 * HIDQ + k], 0.f);
  }
  __syncthreads();

  // ================= DECODER =================
  float qd[2][3];
#pragma unroll
  for (int r = 0; r < 2; ++r) {
    qd[r][0] = (a1w[0] * pt[r][0] + a1w[1] * pt[r][1] + a1w[2] * pt[r][2] + a1b[0]) * QS;
    qd[r][1] = (a1w[3] * pt[r][0] + a1w[4] * pt[r][1] + a1w[5] * pt[r][2] + a1b[1]) * QS;
    qd[r][2] = (a1w[6] * pt[r][0] + a1w[7] * pt[r][1] + a1w[8] * pt[r][2] + a1b[2]) * QS;
  }
  // self-attn with additive tril(ones) mask: seed the exponent with log2(e)
  float dden[2] = {0, 0}, dO[2][3] = {};
  for (int j = 0; j < SPRQ; ++j) {
    const float4 kk = sDecKV[2 * j];
    const float4 vv = sDecKV[2 * j + 1];
#pragma unroll
    for (int r = 0; r < 2; ++r) {
      const int i = t + 64 * r;
      const float m = (j <= i) ? LOG2E : 0.f;
      const float e = exp2f(fmaf(qd[r][0], kk.x, fmaf(qd[r][1], kk.y, fmaf(qd[r][2], kk.z, m))));
      dden[r] += e;
      dO[r][0] = fmaf(e, vv.x, dO[r][0]);
      dO[r][1] = fmaf(e, vv.y, dO[r][1]);
      dO[r][2] = fmaf(e, vv.z, dO[r][2]);
    }
  }
  float dres[2][3];
  s1 = 0.f; s2 = 0.f;
#pragma unroll
  for (int r = 0; r < 2; ++r) {
    const float rd = 1.f / dden[r];
    const float o0 = dO[r][0] * rd, o1 = dO[r][1] * rd, o2 = dO[r][2] * rd;
    dres[r][0] = a1ow[0] * o0 + a1ow[1] * o1 + a1ow[2] * o2 + a1ob[0] + pt[r][0];
    dres[r][1] = a1ow[3] * o0 + a1ow[4] * o1 + a1ow[5] * o2 + a1ob[1] + pt[r][1];
    dres[r][2] = a1ow[6] * o0 + a1ow[7] * o1 + a1ow[8] * o2 + a1ob[2] + pt[r][2];
#pragma unroll
    for (int c = 0; c < 3; ++c) { s1 += dres[r][c]; s2 += dres[r][c] * dres[r][c]; }
  }
  wave_stats(s1, s2, 384.f, mean, rstd);
  float x2d[2][3];
#pragma unroll
  for (int r = 0; r < 2; ++r) {
    const int li = (t + 64 * r) * 3;
#pragma unroll
    for (int c = 0; c < 3; ++c)
      x2d[r][c] = (dres[r][c] - mean) * rstd * dln1w[li + c] + dln1b[li + c];
  }

  // cross-attn, Q=2
#pragma unroll
  for (int r = 0; r < 2; ++r) {
    qd[r][0] = (a2w[0] * x2d[r][0] + a2w[1] * x2d[r][1] + a2w[2] * x2d[r][2] + a2b[0]) * QS;
    qd[r][1] = (a2w[3] * x2d[r][0] + a2w[4] * x2d[r][1] + a2w[5] * x2d[r][2] + a2b[1]) * QS;
    qd[r][2] = (a2w[6] * x2d[r][0] + a2w[7] * x2d[r][1] + a2w[8] * x2d[r][2] + a2b[2]) * QS;
  }
  dden[0] = dden[1] = 0.f;
  dO[0][0] = dO[0][1] = dO[0][2] = dO[1][0] = dO[1][1] = dO[1][2] = 0.f;
  for (int j = 0; j < SINQ; ++j) {
    const float4 kk = sCrossKV[2 * j];
    const float4 vv = sCrossKV[2 * j + 1];
#pragma unroll
    for (int r = 0; r < 2; ++r) {
      const float e = exp2f(fmaf(qd[r][0], kk.x, fmaf(qd[r][1], kk.y, qd[r][2] * kk.z)));
      dden[r] += e;
      dO[r][0] = fmaf(e, vv.x, dO[r][0]);
      dO[r][1] = fmaf(e, vv.y, dO[r][1]);
      dO[r][2] = fmaf(e, vv.z, dO[r][2]);
    }
  }
  s1 = 0.f; s2 = 0.f;
#pragma unroll
  for (int r = 0; r < 2; ++r) {
    const float rd = 1.f / dden[r];
    const float o0 = dO[r][0] * rd, o1 = dO[r][1] * rd, o2 = dO[r][2] * rd;
    dres[r][0] = a2ow[0] * o0 + a2ow[1] * o1 + a2ow[2] * o2 + a2ob[0] + x2d[r][0];
    dres[r][1] = a2ow[3] * o0 + a2ow[4] * o1 + a2ow[5] * o2 + a2ob[1] + x2d[r][1];
    dres[r][2] = a2ow[6] * o0 + a2ow[7] * o1 + a2ow[8] * o2 + a2ob[2] + x2d[r][2];
#pragma unroll
    for (int c = 0; c < 3; ++c) { s1 += dres[r][c]; s2 += dres[r][c] * dres[r][c]; }
  }
  wave_stats(s1, s2, 384.f, mean, rstd);
  float x3[2][3];
#pragma unroll
  for (int r = 0; r < 2; ++r) {
    const int li = (t + 64 * r) * 3;  // dec_ln1 weights AGAIN (per reference)
#pragma unroll
    for (int c = 0; c < 3; ++c)
      x3[r][c] = (dres[r][c] - mean) * rstd * dln1w[li + c] + dln1b[li + c];
  }

  // dec FFN, Q=2
  float dc[2][3] = {};
  for (int k = 0; k < HIDQ; ++k) {
    const float4 wr = sFFN[2 * k];
    const float4 wc = sFFN[2 * k + 1];
#pragma unroll
    for (int r = 0; r < 2; ++r) {
      float h = fmaf(wr.x, x3[r][0], fmaf(wr.y, x3[r][1], fmaf(wr.z, x3[r][2], wr.w)));
      h = fmaxf(h, 0.f);
      dc[r][0] = fmaf(h, wc.x, dc[r][0]);
      dc[r][1] = fmaf(h, wc.y, dc[r][1]);
      dc[r][2] = fmaf(h, wc.z, dc[r][2]);
    }
  }
  s1 = 0.f; s2 = 0.f;
#pragma unroll
  for (int r = 0; r < 2; ++r) {
#pragma unroll
    for (int c = 0; c < 3; ++c) {
      dres[r][c] = dc[r][c] + db2[c] + x3[r][c];
      s1 += dres[r][c]; s2 += dres[r][c] * dres[r][c];
    }
  }
  wave_stats(s1, s2, 384.f, mean, rstd);
#pragma unroll
  for (int r = 0; r < 2; ++r) {
    const int i = t + 64 * r;
    const int li = i * 3;
    float* op = out + ((size_t)b * SPRQ + i) * 3;
#pragma unroll
    for (int c = 0; c < 3; ++c)
      op[c] = (dres[r][c] - mean) * rstd * dln3w[li + c] + dln3b[li + c];
  }
}

extern "C" void kernel_launch(void* const* d_in, const int* in_sizes, int n_in,
                              void* d_out, int out_size, void* d_ws, size_t ws_size,
                              hipStream_t stream) {
  (void)in_sizes; (void)n_in; (void)out_size; (void)d_ws; (void)ws_size;
  fused_fwd<<<NB, 64, 0, stream>>>(
      (const float*)d_in[0],  (const float*)d_in[1],
      (const float*)d_in[2],  (const float*)d_in[3],
      (const float*)d_in[4],  (const float*)d_in[5],
      (const float*)d_in[6],  (const float*)d_in[7],
      (const float*)d_in[8],  (const float*)d_in[9],
      (const float*)d_in[10], (const float*)d_in[11],
      (const float*)d_in[12], (const float*)d_in[13],
      (const float*)d_in[14], (const float*)d_in[15],
      (const float*)d_in[16], (const float*)d_in[17],
      (const float*)d_in[18], (const float*)d_in[19],
      (const float*)d_in[20], (const float*)d_in[21],
      (const float*)d_in[22], (const float*)d_in[23],
      (const float*)d_in[24], (const float*)d_in[25],
      (const float*)d_in[26], (const float*)d_in[27],
      (const float*)d_in[28], (const float*)d_in[29],
      (float*)d_out);
}